// Round 5
// baseline (371.929 us; speedup 1.0000x reference)
//
#include <hip/hip_runtime.h>

#define GLOBAL_AS __attribute__((address_space(1)))
#define LDS_AS    __attribute__((address_space(3)))

typedef __bf16 bf16x8 __attribute__((ext_vector_type(8)));
typedef float  f32x4  __attribute__((ext_vector_type(4)));

// Problem dims (fixed by the reference)
constexpr int SRC_STRIDE = 8192 * 80;         // floats per batch row: 655360
constexpr int TOUT       = 2728;              // output time steps
constexpr long OUT_ELEMS = (long)TOUT * 16 * 1024;  // 44695552
constexpr int SRC_ELEMS  = 32 * SRC_STRIDE;   // 20971520
constexpr int W_ELEMS    = 1024 * 640;        // 655360
constexpr int MBLK       = 682;               // ceil(87296/128)
constexpr int NTILE      = 20;                // 640 / 32 K-tiles
constexpr int SLOTE      = 8192;              // bf16 elems per 16KB slot (A 4096 + B 4096)

__device__ __forceinline__ unsigned short f2bf(float f) {
    union { float f; unsigned u; } a; a.f = f;
    unsigned r = a.u + 0x7FFF + ((a.u >> 16) & 1);   // round-to-nearest-even
    return (unsigned short)(r >> 16);
}

// fp32 -> bf16 conversion, 4 elements/thread
__global__ void cvt_kernel(const float* __restrict__ in, unsigned short* __restrict__ out, int n4) {
    int i = blockIdx.x * blockDim.x + threadIdx.x;
    if (i >= n4) return;
    float4 v = ((const float4*)in)[i];
    ushort4 o;
    o.x = f2bf(v.x); o.y = f2bf(v.y); o.z = f2bf(v.z); o.w = f2bf(v.w);
    ((ushort4*)out)[i] = o;
}

// out_lengths = src_lengths // 3 - 2, written as fp32 after the main output
__global__ void lengths_kernel(const int* __restrict__ len, float* __restrict__ out) {
    int i = threadIdx.x;
    if (i < 32) out[OUT_ELEMS + i] = (float)(len[i] / 3 - 2);
}

#define GLD(gp, lp) __builtin_amdgcn_global_load_lds((const GLOBAL_AS void*)(gp), \
                                                     (LDS_AS void*)(lp), 16, 0, 0)

// stage one K-tile (4 x global_load_lds, 16B/lane) into slot at elem offset soE_
#define STAGE_T(tile_, soE_) do {                               \
    const int kg_ = (tile_) * 32;                               \
    GLD(A  + (aG[0] + kg_), lds + (soE_) + aD0);                \
    GLD(A  + (aG[1] + kg_), lds + (soE_) + aD1);                \
    GLD(Wb + (bG[0] + kg_), lds + (soE_) + bD0);                \
    GLD(Wb + (bG[1] + kg_), lds + (soE_) + bD1);                \
} while (0)

// Fused GEMM (M=87296, N=1024, K=640) + bias + GLU epilogue.
// Geometry = the verified 126.9us baseline: 128x128 tile, 4 waves (2Mx2N),
// 256 threads, per-wave 64x64 output, acc[4][4]. CHANGE: instead of one
// 32KB buffer with a __syncthreads-forced vmcnt(0) drain per K-step, use
// THREE rotating 16KB slots (BK=32, prefetch depth 2) with counted
// s_waitcnt vmcnt(4) + raw s_barrier per tile. LDS = 48KB -> still
// 3 blocks/CU (the baseline's TLP, which rounds 1-3 lost at 1 block/CU).
// Slot discipline: tile t reads slot t%3; stages tile t+2 into slot
// (t+2)%3 == (t-1)%3, which was last read in tile t-1 and is free after
// the t-1 boundary barrier (reads complete before that wave's lgkmcnt(0)).
// Read-after-write: boundary of t-1 waits vmcnt(4) -> per-wave slices of
// tile t landed; barrier makes it collective.
// LDS layout per slot (verified in rounds 0-3): A = 64 lines x 64 bf16
// (line = 2 rows of K=32), B same at +4096 elems. Chunk-XOR swizzle:
// physical 16B-chunk p of line L holds logical chunk c = p ^ (L&7);
// conflict-free for both the linear DMA write and the ds_read_b128 frags.
__global__ __launch_bounds__(256, 3)
void glu_gemm(const __bf16* __restrict__ A,
              const __bf16* __restrict__ Wb,
              const float* __restrict__ bias,
              float* __restrict__ out) {
    __shared__ __bf16 lds[3 * SLOTE];   // 48 KiB

    const int tid  = threadIdx.x;
    const int lane = tid & 63;
    const int w    = tid >> 6;        // wave 0..3
    const int wm   = w & 1;           // wave M position (2x2 wave grid)
    const int wn   = w >> 1;

    // XCD-aware swizzle (baseline-verified): all 8 bn-siblings of one bm
    // share bid%8 -> same XCD L2, consecutive numbering.
    const int bid = blockIdx.x;
    const int bn  = (bid >> 3) & 7;
    const int bm  = (bid >> 6) * 8 + (bid & 7);
    if (bm >= MBLK) return;           // 48 idle tail blocks; block-uniform exit

    // ---- staging lane constants (verified form) ----
    // one wave-load covers 8 lines (16 rows): lane -> line (lane>>3), phys chunk (lane&7)
    const int sl  = lane >> 3;
    const int sp  = lane & 7;
    const int sc  = sp ^ sl;          // logical c' = (row-parity)*4 + k-chunk
    const int scc = (sc & 3) * 8;     // k element offset within 32-wide tile
    const int srp = sc >> 2;          // row parity
    int aG[2], bG[2];
#pragma unroll
    for (int h = 0; h < 2; ++h) {
        int R = 2 * (h * 32 + w * 8 + sl) + srp;   // row within 128-row tile
        int m = bm * 128 + R;
        aG[h] = (m & 31) * SRC_STRIDE + (m >> 5) * 240 + scc;
        int n = bn * 128 + R;
        bG[h] = n * 640 + scc;
    }
    const int aD0 = (w * 8) * 64;             // LDS dest bases (elems, wave-uniform)
    const int aD1 = (32 + w * 8) * 64;
    const int bD0 = 4096 + aD0;
    const int bD1 = 4096 + aD1;

    // ---- fragment read constants (verified form) ----
    // A-frag mf: row R' = wm*64 + mf*16 + (lane&15), k-chunk q = lane>>4
    // line = R'>>1; c' = (R'&1)*4 + q; phys = c' ^ (line&7); line&7 == ll
    const int q   = lane >> 4;
    const int ll  = (lane & 15) >> 1;
    const int pfr = (((lane & 1) << 2) | q) ^ ll;
    const int aB  = (wm * 32 + ll) * 64 + pfr * 8;          // elems; +mf*512
    const int bB  = 4096 + (wn * 32 + ll) * 64 + pfr * 8;   // elems; +nf*512

    const unsigned LB    = (unsigned)(unsigned long long)(&lds[0]);
    const unsigned adrA0 = LB + 2u * (unsigned)aB;
    const unsigned adrB0 = LB + 2u * (unsigned)bB;

    f32x4 acc[4][4] = {};

    // slot elem offsets: cur = read slot of tile t, nxt = t+1, prv = stage target
    unsigned curE = 0, nxtE = SLOTE, prvE = 2 * SLOTE;

    // ---- prologue: stage tiles 0,1 into slots 0,1 (8 loads in flight) ----
    STAGE_T(0, 0);
    STAGE_T(1, SLOTE);
    __builtin_amdgcn_sched_barrier(0);
    asm volatile("s_waitcnt vmcnt(4)");        // tile 0 landed; tile 1 in flight
    __builtin_amdgcn_sched_barrier(0);
    __builtin_amdgcn_s_barrier();

    // ---- main loop: 20 K-tiles ----
#pragma unroll 1
    for (int t = 0; t < NTILE; ++t) {
        if (t < NTILE - 2) STAGE_T(t + 2, prvE);   // stage into freed slot

        const unsigned aAdr = adrA0 + 2u * curE;
        const unsigned bAdr = adrB0 + 2u * curE;
        bf16x8 af0, af1, af2, af3, bf0, bf1, bf2, bf3;
        asm volatile("ds_read_b128 %0, %1 offset:0"    : "=v"(af0) : "v"(aAdr));
        asm volatile("ds_read_b128 %0, %1 offset:1024" : "=v"(af1) : "v"(aAdr));
        asm volatile("ds_read_b128 %0, %1 offset:2048" : "=v"(af2) : "v"(aAdr));
        asm volatile("ds_read_b128 %0, %1 offset:3072" : "=v"(af3) : "v"(aAdr));
        asm volatile("ds_read_b128 %0, %1 offset:0"    : "=v"(bf0) : "v"(bAdr));
        asm volatile("ds_read_b128 %0, %1 offset:1024" : "=v"(bf1) : "v"(bAdr));
        asm volatile("ds_read_b128 %0, %1 offset:2048" : "=v"(bf2) : "v"(bAdr));
        asm volatile("ds_read_b128 %0, %1 offset:3072" : "=v"(bf3) : "v"(bAdr));
        __builtin_amdgcn_sched_barrier(0);
        asm volatile("s_waitcnt lgkmcnt(0)");
        __builtin_amdgcn_sched_barrier(0);     // rule #18: keep MFMAs below the wait

        __builtin_amdgcn_s_setprio(1);
#pragma unroll
        for (int mt = 0; mt < 4; ++mt) {
            acc[mt][0] = __builtin_amdgcn_mfma_f32_16x16x32_bf16(
                (mt==0?af0:mt==1?af1:mt==2?af2:af3), bf0, acc[mt][0], 0, 0, 0);
            acc[mt][1] = __builtin_amdgcn_mfma_f32_16x16x32_bf16(
                (mt==0?af0:mt==1?af1:mt==2?af2:af3), bf1, acc[mt][1], 0, 0, 0);
            acc[mt][2] = __builtin_amdgcn_mfma_f32_16x16x32_bf16(
                (mt==0?af0:mt==1?af1:mt==2?af2:af3), bf2, acc[mt][2], 0, 0, 0);
            acc[mt][3] = __builtin_amdgcn_mfma_f32_16x16x32_bf16(
                (mt==0?af0:mt==1?af1:mt==2?af2:af3), bf3, acc[mt][3], 0, 0, 0);
        }
        __builtin_amdgcn_s_setprio(0);
        __builtin_amdgcn_sched_barrier(0);

        // boundary: ensure tile t+1 landed (collectively, via barrier); keep
        // the newest stage (4 loads) in flight. Never vmcnt(0) until drain.
        if (t < NTILE - 2)       { asm volatile("s_waitcnt vmcnt(4)"); }
        else if (t == NTILE - 2) { asm volatile("s_waitcnt vmcnt(0)"); }
        __builtin_amdgcn_sched_barrier(0);
        if (t < NTILE - 1) __builtin_amdgcn_s_barrier();

        const unsigned tmp = prvE; prvE = curE; curE = nxtE; nxtE = tmp;
    }

    // ---- epilogue (baseline-verified): bias + GLU ----
    const int col = lane & 15;
    float bv[4];
#pragma unroll
    for (int nt = 0; nt < 4; ++nt)
        bv[nt] = bias[bn * 128 + wn * 64 + nt * 16 + col];

    const int t_base = bm * 4 + wm * 2;
#pragma unroll
    for (int pr = 0; pr < 2; ++pr) {                   // two t-groups per wave tile
        const int t = t_base + pr;
#pragma unroll
        for (int nt = 0; nt < 4; ++nt) {
            const int n = bn * 128 + wn * 64 + nt * 16 + col;
#pragma unroll
            for (int r2 = 0; r2 < 4; ++r2) {
                const int brow = q * 4 + r2;           // b in 0..15 (value rows)
                float v = acc[pr * 2 + 0][nt][r2] + bv[nt];
                float g = acc[pr * 2 + 1][nt][r2] + bv[nt];
                float s = 1.0f / (1.0f + __expf(-g));
                out[((long)(t * 16 + brow)) * 1024 + n] = v * s;
            }
        }
    }
}

extern "C" void kernel_launch(void* const* d_in, const int* in_sizes, int n_in,
                              void* d_out, int out_size, void* d_ws, size_t ws_size,
                              hipStream_t stream) {
    const float* src  = (const float*)d_in[0];
    const int*   lens = (const int*)d_in[1];
    const float* Wf   = (const float*)d_in[2];
    const float* bias = (const float*)d_in[3];
    float* out = (float*)d_out;

    unsigned short* srcb = (unsigned short*)d_ws;          // 20971520 bf16 = 41.9 MB
    unsigned short* wb   = srcb + SRC_ELEMS;               // 655360 bf16 = 1.3 MB

    // bf16 pre-pass (src + W)
    cvt_kernel<<<SRC_ELEMS / 4 / 256, 256, 0, stream>>>(src, srcb, SRC_ELEMS / 4);
    cvt_kernel<<<W_ELEMS / 4 / 256, 256, 0, stream>>>(Wf, wb, W_ELEMS / 4);

    // out_lengths
    lengths_kernel<<<1, 64, 0, stream>>>(lens, out);

    // fused GEMM + GLU: 86 groups x (8 bn x 8 bm_local) = 5504 blocks (48 idle tail)
    glu_gemm<<<86 * 64, 256, 0, stream>>>((const __bf16*)srcb, (const __bf16*)wb, bias, out);
}